// Round 16
// baseline (979.815 us; speedup 1.0000x reference)
//
#include <hip/hip_runtime.h>

#define NL 16
#define NT 2048
#define NH 2048
#define NF 512
#define NPAIR 136

typedef short bf16x8 __attribute__((ext_vector_type(8)));
typedef float f32x4 __attribute__((ext_vector_type(4)));
typedef short s16x4 __attribute__((ext_vector_type(4)));
typedef unsigned u32x4 __attribute__((ext_vector_type(4)));

__device__ __forceinline__ short f2bf(float f) {
  union { float f; unsigned u; } x; x.f = f;
  unsigned r = (x.u + 0x7fffu + ((x.u >> 16) & 1u)) >> 16;
  return (short)r;
}

__device__ __forceinline__ unsigned cvtpk(float a, float b) {
  unsigned r;
  asm("v_cvt_pk_bf16_f32 %0, %1, %2" : "=v"(r) : "v"(a), "v"(b));
  return r;
}

// ---------------- conversion kernels (r12) ----------------

__global__ void k_cvt_f32_bf16(const float* __restrict__ src, short* __restrict__ dst, int n4) {
  int i = blockIdx.x * blockDim.x + threadIdx.x;
  const int stride = gridDim.x * blockDim.x;
  for (; i < n4; i += stride) {
    const float4 v = reinterpret_cast<const float4*>(src)[i];
    s16x4 o;
    o[0] = f2bf(v.x); o[1] = f2bf(v.y); o[2] = f2bf(v.z); o[3] = f2bf(v.w);
    reinterpret_cast<s16x4*>(dst)[i] = o;
  }
}

__global__ void k_cvt_wdec(const float* __restrict__ wdec, short* __restrict__ dst) {
  const int p = blockIdx.y;
  int l = 0;
  while ((l + 1) * (l + 2) / 2 <= p) ++l;
  const int s = p - l * (l + 1) / 2;
  const float* src = wdec + (size_t)(s * NL + l) * (NH * NF);
  short* d = dst + (size_t)p * (NH * NF);
  const int n4 = NH * NF / 4;
  for (int i = blockIdx.x * blockDim.x + threadIdx.x; i < n4; i += gridDim.x * blockDim.x) {
    const float4 v = reinterpret_cast<const float4*>(src)[i];
    s16x4 o;
    o[0] = f2bf(v.x); o[1] = f2bf(v.y); o[2] = f2bf(v.z); o[3] = f2bf(v.w);
    reinterpret_cast<s16x4*>(d)[i] = o;
  }
}

// ---------------- shared swizzled-LDS primitives ----------------
// Swizzle: element (r, cbyte) at LDS byte ((r<<7)|cbyte) ^ ((r&7)<<4); rows 128B.

__device__ __forceinline__ bf16x8 lds_frag(const short* slot, int r, int cbyte) {
  int byte = (r << 7) + cbyte;
  byte ^= (r & 7) << 4;
  return *reinterpret_cast<const bf16x8*>(reinterpret_cast<const char*>(slot) + byte);
}

// ================= ENCODE (r12 exactly: 256^2, 8 waves, fused f32-A staging) ====

__device__ __forceinline__ void stage_half(short* slot, const short* gbase, int ld,
                                           int isA, int h, int tid, int wave) {
#pragma unroll
  for (int j = 0; j < 2; ++j) {
    const int o = j * 8192 + tid * 16;
    const int r = o >> 7;
    const int cb = (o ^ ((r & 7) << 4)) & 127;
    const int g = isA ? (((r >> 6) << 7) + h * 64 + (r & 63))
                      : (((r >> 5) << 6) + h * 32 + (r & 31));
    __builtin_amdgcn_global_load_lds(
        (const __attribute__((address_space(1))) void*)(gbase + (size_t)g * ld + (cb >> 1)),
        (__attribute__((address_space(3))) void*)((char*)slot + j * 8192 + wave * 1024),
        16, 0, 0);
  }
}

struct F32Half { float4 q[2][2]; };

__device__ __forceinline__ void issue_f32half(F32Half& st, const float* gbase, int ld,
                                              int isA, int h, int tid) {
#pragma unroll
  for (int j = 0; j < 2; ++j) {
    const int o = j * 8192 + tid * 16;
    const int r = o >> 7;
    const int cb = (o ^ ((r & 7) << 4)) & 127;
    const int g = isA ? (((r >> 6) << 7) + h * 64 + (r & 63))
                      : (((r >> 5) << 6) + h * 32 + (r & 31));
    const float* p = gbase + (size_t)g * ld + (cb >> 1);
    st.q[j][0] = *reinterpret_cast<const float4*>(p);
    st.q[j][1] = *reinterpret_cast<const float4*>(p + 4);
  }
}

__device__ __forceinline__ void commit_f32half(const F32Half& st, short* slot, int tid) {
#pragma unroll
  for (int j = 0; j < 2; ++j) {
    u32x4 o;
    o[0] = cvtpk(st.q[j][0].x, st.q[j][0].y);
    o[1] = cvtpk(st.q[j][0].z, st.q[j][0].w);
    o[2] = cvtpk(st.q[j][1].x, st.q[j][1].y);
    o[3] = cvtpk(st.q[j][1].z, st.q[j][1].w);
    *reinterpret_cast<u32x4*>((char*)slot + j * 8192 + tid * 16) = o;
  }
}

template <typename IFn, typename CFn>
__device__ __forceinline__ void ktile_flat(short (*bufc)[8192], f32x4 (&acc)[2][2][4][2],
                                           int wr, int wc, int lane, IFn issue, CFn commit) {
  const int lr = lane & 15;
  const int ko = (lane >> 4) * 16;
  issue();
  bf16x8 b0[2][2], b1[2][2], a0[2][4], a1[2][4];
#pragma unroll
  for (int kk = 0; kk < 2; ++kk) {
#pragma unroll
    for (int n = 0; n < 2; ++n) {
      b0[kk][n] = lds_frag(bufc[2], wc * 32 + n * 16 + lr, kk * 64 + ko);
      b1[kk][n] = lds_frag(bufc[3], wc * 32 + n * 16 + lr, kk * 64 + ko);
    }
#pragma unroll
    for (int m = 0; m < 4; ++m)
      a0[kk][m] = lds_frag(bufc[0], wr * 64 + m * 16 + lr, kk * 64 + ko);
  }
  __builtin_amdgcn_s_setprio(1);
#pragma unroll
  for (int kk = 0; kk < 2; ++kk)
#pragma unroll
    for (int m = 0; m < 4; ++m)
#pragma unroll
      for (int n = 0; n < 2; ++n) {
        acc[0][0][m][n] = __builtin_amdgcn_mfma_f32_16x16x32_bf16(a0[kk][m], b0[kk][n],
                                                                  acc[0][0][m][n], 0, 0, 0);
        acc[0][1][m][n] = __builtin_amdgcn_mfma_f32_16x16x32_bf16(a0[kk][m], b1[kk][n],
                                                                  acc[0][1][m][n], 0, 0, 0);
      }
  __builtin_amdgcn_s_setprio(0);
#pragma unroll
  for (int kk = 0; kk < 2; ++kk)
#pragma unroll
    for (int m = 0; m < 4; ++m)
      a1[kk][m] = lds_frag(bufc[1], wr * 64 + m * 16 + lr, kk * 64 + ko);
  __builtin_amdgcn_s_setprio(1);
#pragma unroll
  for (int kk = 0; kk < 2; ++kk)
#pragma unroll
    for (int m = 0; m < 4; ++m)
#pragma unroll
      for (int n = 0; n < 2; ++n) {
        acc[1][0][m][n] = __builtin_amdgcn_mfma_f32_16x16x32_bf16(a1[kk][m], b0[kk][n],
                                                                  acc[1][0][m][n], 0, 0, 0);
        acc[1][1][m][n] = __builtin_amdgcn_mfma_f32_16x16x32_bf16(a1[kk][m], b1[kk][n],
                                                                  acc[1][1][m][n], 0, 0, 0);
      }
  __builtin_amdgcn_s_setprio(0);
  commit();
  asm volatile("s_waitcnt vmcnt(0) lgkmcnt(0)" ::: "memory");
  __builtin_amdgcn_s_barrier();
}

__global__ __launch_bounds__(512, 2) void k_encode256(const float* __restrict__ xf,
                                                      const short* __restrict__ webf,
                                                      float* __restrict__ feats_f32,
                                                      short* __restrict__ feats_bf) {
  __shared__ short lds[2][4][8192];
  const int l = blockIdx.z;
  const int row0 = blockIdx.y * 256;
  const int col0 = blockIdx.x * 256;
  const int tid = threadIdx.x;
  const int wave = tid >> 6, lane = tid & 63;
  const int wr = wave >> 2, wc = wave & 3;

  const float* A = xf + (size_t)l * NT * NH + (size_t)row0 * NH;
  const short* B = webf + (size_t)l * NF * NH + (size_t)col0 * NH;

  f32x4 acc[2][2][4][2];
#pragma unroll
  for (int qa = 0; qa < 2; ++qa)
#pragma unroll
    for (int qb = 0; qb < 2; ++qb)
#pragma unroll
      for (int m = 0; m < 4; ++m)
#pragma unroll
        for (int n = 0; n < 2; ++n) {
          f32x4 z = {0.f, 0.f, 0.f, 0.f};
          acc[qa][qb][m][n] = z;
        }

  const int KT = NH / 64;
  F32Half stA0, stA1;
  issue_f32half(stA0, A, NH, 1, 0, tid);
  issue_f32half(stA1, A, NH, 1, 1, tid);
  stage_half(lds[0][2], B, NH, 0, 0, tid, wave);
  stage_half(lds[0][3], B, NH, 0, 1, tid, wave);
  commit_f32half(stA0, lds[0][0], tid);
  commit_f32half(stA1, lds[0][1], tid);
  asm volatile("s_waitcnt vmcnt(0) lgkmcnt(0)" ::: "memory");
  __builtin_amdgcn_s_barrier();

  for (int u = 0; u < KT; ++u) {
    short(*bufc)[8192] = lds[u & 1];
    short(*bufn)[8192] = lds[(u + 1) & 1];
    ktile_flat(bufc, acc, wr, wc, lane,
        [&] {
          if (u + 1 < KT) {
            issue_f32half(stA0, A + (u + 1) * 64, NH, 1, 0, tid);
            issue_f32half(stA1, A + (u + 1) * 64, NH, 1, 1, tid);
            stage_half(bufn[2], B + (u + 1) * 64, NH, 0, 0, tid, wave);
            stage_half(bufn[3], B + (u + 1) * 64, NH, 0, 1, tid, wave);
          }
        },
        [&] {
          if (u + 1 < KT) {
            commit_f32half(stA0, bufn[0], tid);
            commit_f32half(stA1, bufn[1], tid);
          }
        });
  }

  const int lr4 = (lane >> 4) * 4, lc = lane & 15;
  float* outF = feats_f32 + (size_t)l * NT * NF;
  short* outB = feats_bf + (size_t)l * NT * NF;
#pragma unroll
  for (int qa = 0; qa < 2; ++qa)
#pragma unroll
    for (int qb = 0; qb < 2; ++qb)
#pragma unroll
      for (int m = 0; m < 4; ++m)
#pragma unroll
        for (int n = 0; n < 2; ++n)
#pragma unroll
          for (int rg = 0; rg < 4; ++rg) {
            const int rr = row0 + wr * 128 + qa * 64 + m * 16 + lr4 + rg;
            const int cc = col0 + wc * 64 + qb * 32 + n * 16 + lc;
            float v = acc[qa][qb][m][n][rg];
            v = v > 0.f ? v : 0.f;
            outF[(size_t)rr * NF + cc] = v;
            outB[(size_t)rr * NF + cc] = f2bf(v);
          }
}

// ================= DECODE (NEW: 128^2 tile, 4 waves, 64KB LDS, 2 blocks/CU) =====
// Mechanism: two independent barrier domains per CU. All prior schedule nulls
// (r3/r4/r9/r10/r14) shared ONE barrier domain (128KB LDS -> 1 block/CU), so
// LDS-port time (~2300cyc/tile) and MFMA time (~620) serialized. Two blocks
// alternate: one block's drain/barrier stall fills with the other's MFMA.
// Geometry honors r13's VGPR lesson: per-wave out 64x64 -> acc 64 VGPR,
// frags 64, total ~140 << 256 (2 waves/SIMD cap). LDS 2buf x (A+B) x 16KB.
// Ledger: flat drain-to-0 per tile (stages target other buffer; one barrier).
// Grid (16,16,16): x=col (B-panel siblings y-stride 16 ≡ same XCD), z: l=15-z.

__device__ __forceinline__ void stage_panel128(short* panel, const short* gbase, int ld,
                                               int tid, int wave) {
#pragma unroll
  for (int j = 0; j < 4; ++j) {
    const int o = j * 4096 + tid * 16;              // linear LDS byte offset
    const int r = o >> 7;                           // row (0..127)
    const int cb = (o ^ ((r & 7) << 4)) & 127;      // pre-swizzled source col-byte
    __builtin_amdgcn_global_load_lds(
        (const __attribute__((address_space(1))) void*)(gbase + (size_t)r * ld + (cb >> 1)),
        (__attribute__((address_space(3))) void*)((char*)panel + j * 4096 + wave * 1024),
        16, 0, 0);
  }
}

template <typename SFn>
__device__ __forceinline__ void ktile128(short (*bufc)[8192], f32x4 (&acc)[4][4],
                                         int wr, int wc, int lane, SFn stagefn) {
  const int lr = lane & 15;
  const int ko = (lane >> 4) * 16;
  stagefn();  // 8 gload_lds into the OTHER buffer — issued first
  bf16x8 a[2][4], b[2][4];
#pragma unroll
  for (int kk = 0; kk < 2; ++kk) {
#pragma unroll
    for (int n = 0; n < 4; ++n)
      b[kk][n] = lds_frag(bufc[1], wc * 64 + n * 16 + lr, kk * 64 + ko);
#pragma unroll
    for (int m = 0; m < 4; ++m)
      a[kk][m] = lds_frag(bufc[0], wr * 64 + m * 16 + lr, kk * 64 + ko);
  }
  __builtin_amdgcn_s_setprio(1);
#pragma unroll
  for (int kk = 0; kk < 2; ++kk)
#pragma unroll
    for (int m = 0; m < 4; ++m)
#pragma unroll
      for (int n = 0; n < 4; ++n)
        acc[m][n] = __builtin_amdgcn_mfma_f32_16x16x32_bf16(a[kk][m], b[kk][n],
                                                            acc[m][n], 0, 0, 0);
  __builtin_amdgcn_s_setprio(0);
  asm volatile("s_waitcnt vmcnt(0) lgkmcnt(0)" ::: "memory");
  __builtin_amdgcn_s_barrier();
}

__global__ __launch_bounds__(256, 2) void k_decode128(const short* __restrict__ featsbf,
                                                      const short* __restrict__ wdbf,
                                                      float* __restrict__ recon) {
  __shared__ short lds[2][2][8192];  // 64 KB -> 2 blocks/CU
  const int l = (NL - 1) - blockIdx.z;  // heavy-first
  const int row0 = blockIdx.y * 128;    // T
  const int col0 = blockIdx.x * 128;    // H
  const int tid = threadIdx.x;
  const int wave = tid >> 6, lane = tid & 63;
  const int wr = wave >> 1, wc = wave & 1;
  const int pbase = l * (l + 1) / 2;

  const short* Af = featsbf + (size_t)row0 * NF;
  const short* Bw = wdbf + (size_t)col0 * NF;

  f32x4 acc[4][4];
#pragma unroll
  for (int m = 0; m < 4; ++m)
#pragma unroll
    for (int n = 0; n < 4; ++n) {
      f32x4 z = {0.f, 0.f, 0.f, 0.f};
      acc[m][n] = z;
    }

  const int KT = 8 * (l + 1);
#define ABASE(kt) (Af + (size_t)((kt) >> 3) * (NT * NF) + ((kt)&7) * 64)
#define BBASE(kt) (Bw + (size_t)(pbase + ((kt) >> 3)) * (NH * NF) + ((kt)&7) * 64)

  stage_panel128(lds[0][0], ABASE(0), NF, tid, wave);
  stage_panel128(lds[0][1], BBASE(0), NF, tid, wave);
  asm volatile("s_waitcnt vmcnt(0)" ::: "memory");
  __builtin_amdgcn_s_barrier();

  for (int u = 0; u < KT; ++u) {
    short(*bufc)[8192] = lds[u & 1];
    short(*bufn)[8192] = lds[(u + 1) & 1];
    ktile128(bufc, acc, wr, wc, lane, [&] {
      if (u + 1 < KT) {
        stage_panel128(bufn[0], ABASE(u + 1), NF, tid, wave);
        stage_panel128(bufn[1], BBASE(u + 1), NF, tid, wave);
      }
    });
  }
#undef ABASE
#undef BBASE

  const int lr4 = (lane >> 4) * 4, lc = lane & 15;
  float* out = recon + (size_t)l * NT * NH;
#pragma unroll
  for (int m = 0; m < 4; ++m)
#pragma unroll
    for (int n = 0; n < 4; ++n)
#pragma unroll
      for (int rg = 0; rg < 4; ++rg) {
        const int rr = row0 + wr * 64 + m * 16 + lr4 + rg;
        const int cc = col0 + wc * 64 + n * 16 + lc;
        out[(size_t)rr * NH + cc] = acc[m][n][rg];
      }
}

// ---------------- launch ----------------

extern "C" void kernel_launch(void* const* d_in, const int* in_sizes, int n_in,
                              void* d_out, int out_size, void* d_ws, size_t ws_size,
                              hipStream_t stream) {
  const float* x = (const float*)d_in[0];
  const float* wenc = (const float*)d_in[1];
  const float* wdec = (const float*)d_in[2];

  float* feats_f32 = (float*)d_out;
  float* recon = feats_f32 + (size_t)NL * NT * NF;

  short* we_bf = (short*)d_ws;                           // 32 MiB
  short* wd_bf = we_bf + (size_t)NL * NF * NH;           // 272 MiB
  short* ft_bf = wd_bf + (size_t)NPAIR * NH * NF;        // 32 MiB

  k_cvt_f32_bf16<<<1024, 256, 0, stream>>>(wenc, we_bf, NL * NF * NH / 4);
  k_cvt_wdec<<<dim3(512, NPAIR), 256, 0, stream>>>(wdec, wd_bf);

  k_encode256<<<dim3(2, 8, 16), 512, 0, stream>>>(x, we_bf, feats_f32, ft_bf);
  k_decode128<<<dim3(16, 16, 16), 256, 0, stream>>>(ft_bf, wd_bf, recon);
}

// Round 17
// 818.639 us; speedup vs baseline: 1.1969x; 1.1969x over previous
//
#include <hip/hip_runtime.h>

#define NL 16
#define NT 2048
#define NH 2048
#define NF 512
#define NPAIR 136

typedef short bf16x8 __attribute__((ext_vector_type(8)));
typedef float f32x4 __attribute__((ext_vector_type(4)));
typedef short s16x4 __attribute__((ext_vector_type(4)));
typedef unsigned u32x4 __attribute__((ext_vector_type(4)));

__device__ __forceinline__ short f2bf(float f) {
  union { float f; unsigned u; } x; x.f = f;
  unsigned r = (x.u + 0x7fffu + ((x.u >> 16) & 1u)) >> 16;
  return (short)r;
}

__device__ __forceinline__ unsigned cvtpk(float a, float b) {
  unsigned r;
  asm("v_cvt_pk_bf16_f32 %0, %1, %2" : "=v"(r) : "v"(a), "v"(b));
  return r;
}

// ---------------- conversion kernels ----------------

__global__ void k_cvt_f32_bf16(const float* __restrict__ src, short* __restrict__ dst, int n4) {
  int i = blockIdx.x * blockDim.x + threadIdx.x;
  const int stride = gridDim.x * blockDim.x;
  for (; i < n4; i += stride) {
    const float4 v = reinterpret_cast<const float4*>(src)[i];
    s16x4 o;
    o[0] = f2bf(v.x); o[1] = f2bf(v.y); o[2] = f2bf(v.z); o[3] = f2bf(v.w);
    reinterpret_cast<s16x4*>(dst)[i] = o;
  }
}

__global__ void k_cvt_wdec(const float* __restrict__ wdec, short* __restrict__ dst) {
  const int p = blockIdx.y;
  int l = 0;
  while ((l + 1) * (l + 2) / 2 <= p) ++l;
  const int s = p - l * (l + 1) / 2;
  const float* src = wdec + (size_t)(s * NL + l) * (NH * NF);
  short* d = dst + (size_t)p * (NH * NF);
  const int n4 = NH * NF / 4;
  for (int i = blockIdx.x * blockDim.x + threadIdx.x; i < n4; i += gridDim.x * blockDim.x) {
    const float4 v = reinterpret_cast<const float4*>(src)[i];
    s16x4 o;
    o[0] = f2bf(v.x); o[1] = f2bf(v.y); o[2] = f2bf(v.z); o[3] = f2bf(v.w);
    reinterpret_cast<s16x4*>(d)[i] = o;
  }
}

// ---------------- 256x256 GEMM, flat K-tile (ONE barrier per tile) ----------------
// 8 waves: wr=wave>>2, wc=wave&3. Per-wave out 128x64, quadrants (qa,qb).
// LDS: lds[buf][slot][8192 shorts]; slot 0=A-half0, 1=A-half1, 2=B-half0, 3=B-half1.
//   A-half(h) local row r <-> tile row (r>>6)*128 + h*64 + (r&63)
//   B-half(h) local row r <-> tile row (r>>5)*64  + h*32 + (r&31)
// Swizzle: element (r, cbyte) at LDS byte ((r<<7)|cbyte) ^ ((r&7)<<4).
// Ledger (drain-to-0 per tile): WAR — stages target the OTHER buffer whose last
// reads were lgkm-drained before the previous barrier. RAW — full vmcnt/lgkm
// drain at tile end retires all staging before any wave enters the next tile.
// Session conclusions baked in: reg-staged f32 fusion only for L3-resident
// streams (encode's x — r11); 256^2/8-wave is hard-locked to 1 block/CU by the
// 128-VGPR accumulator (r13); smaller tiles raise traffic and lose (r16);
// schedule micro-structure is saturated (r3-r14 nulls).

__device__ __forceinline__ bf16x8 lds_frag(const short* slot, int r, int cbyte) {
  int byte = (r << 7) + cbyte;
  byte ^= (r & 7) << 4;
  return *reinterpret_cast<const bf16x8*>(reinterpret_cast<const char*>(slot) + byte);
}

__device__ __forceinline__ void stage_half(short* slot, const short* gbase, int ld,
                                           int isA, int h, int tid, int wave) {
#pragma unroll
  for (int j = 0; j < 2; ++j) {
    const int o = j * 8192 + tid * 16;
    const int r = o >> 7;
    const int cb = (o ^ ((r & 7) << 4)) & 127;
    const int g = isA ? (((r >> 6) << 7) + h * 64 + (r & 63))
                      : (((r >> 5) << 6) + h * 32 + (r & 31));
    __builtin_amdgcn_global_load_lds(
        (const __attribute__((address_space(1))) void*)(gbase + (size_t)g * ld + (cb >> 1)),
        (__attribute__((address_space(3))) void*)((char*)slot + j * 8192 + wave * 1024),
        16, 0, 0);
  }
}

struct F32Half { float4 q[2][2]; };

__device__ __forceinline__ void issue_f32half(F32Half& st, const float* gbase, int ld,
                                              int isA, int h, int tid) {
#pragma unroll
  for (int j = 0; j < 2; ++j) {
    const int o = j * 8192 + tid * 16;
    const int r = o >> 7;
    const int cb = (o ^ ((r & 7) << 4)) & 127;
    const int g = isA ? (((r >> 6) << 7) + h * 64 + (r & 63))
                      : (((r >> 5) << 6) + h * 32 + (r & 31));
    const float* p = gbase + (size_t)g * ld + (cb >> 1);
    st.q[j][0] = *reinterpret_cast<const float4*>(p);
    st.q[j][1] = *reinterpret_cast<const float4*>(p + 4);
  }
}

__device__ __forceinline__ void commit_f32half(const F32Half& st, short* slot, int tid) {
#pragma unroll
  for (int j = 0; j < 2; ++j) {
    u32x4 o;
    o[0] = cvtpk(st.q[j][0].x, st.q[j][0].y);
    o[1] = cvtpk(st.q[j][0].z, st.q[j][0].w);
    o[2] = cvtpk(st.q[j][1].x, st.q[j][1].y);
    o[3] = cvtpk(st.q[j][1].z, st.q[j][1].w);
    *reinterpret_cast<u32x4*>((char*)slot + j * 8192 + tid * 16) = o;
  }
}

template <typename IFn, typename CFn>
__device__ __forceinline__ void ktile_flat(short (*bufc)[8192], f32x4 (&acc)[2][2][4][2],
                                           int wr, int wc, int lane, IFn issue, CFn commit) {
  const int lr = lane & 15;
  const int ko = (lane >> 4) * 16;
  issue();  // global loads for tile u+1 — issued first, max latency slack
  bf16x8 b0[2][2], b1[2][2], a0[2][4], a1[2][4];
#pragma unroll
  for (int kk = 0; kk < 2; ++kk) {
#pragma unroll
    for (int n = 0; n < 2; ++n) {
      b0[kk][n] = lds_frag(bufc[2], wc * 32 + n * 16 + lr, kk * 64 + ko);
      b1[kk][n] = lds_frag(bufc[3], wc * 32 + n * 16 + lr, kk * 64 + ko);
    }
#pragma unroll
    for (int m = 0; m < 4; ++m)
      a0[kk][m] = lds_frag(bufc[0], wr * 64 + m * 16 + lr, kk * 64 + ko);
  }
  __builtin_amdgcn_s_setprio(1);
#pragma unroll
  for (int kk = 0; kk < 2; ++kk)
#pragma unroll
    for (int m = 0; m < 4; ++m)
#pragma unroll
      for (int n = 0; n < 2; ++n) {
        acc[0][0][m][n] = __builtin_amdgcn_mfma_f32_16x16x32_bf16(a0[kk][m], b0[kk][n],
                                                                  acc[0][0][m][n], 0, 0, 0);
        acc[0][1][m][n] = __builtin_amdgcn_mfma_f32_16x16x32_bf16(a0[kk][m], b1[kk][n],
                                                                  acc[0][1][m][n], 0, 0, 0);
      }
  __builtin_amdgcn_s_setprio(0);
#pragma unroll
  for (int kk = 0; kk < 2; ++kk)
#pragma unroll
    for (int m = 0; m < 4; ++m)
      a1[kk][m] = lds_frag(bufc[1], wr * 64 + m * 16 + lr, kk * 64 + ko);
  __builtin_amdgcn_s_setprio(1);
#pragma unroll
  for (int kk = 0; kk < 2; ++kk)
#pragma unroll
    for (int m = 0; m < 4; ++m)
#pragma unroll
      for (int n = 0; n < 2; ++n) {
        acc[1][0][m][n] = __builtin_amdgcn_mfma_f32_16x16x32_bf16(a1[kk][m], b0[kk][n],
                                                                  acc[1][0][m][n], 0, 0, 0);
        acc[1][1][m][n] = __builtin_amdgcn_mfma_f32_16x16x32_bf16(a1[kk][m], b1[kk][n],
                                                                  acc[1][1][m][n], 0, 0, 0);
      }
  __builtin_amdgcn_s_setprio(0);
  commit();  // encode: cvt+ds_write staged f32 halves; decode: no-op
  asm volatile("s_waitcnt vmcnt(0) lgkmcnt(0)" ::: "memory");
  __builtin_amdgcn_s_barrier();
}

// ---------------- encode: feats[l] = relu(x[l] @ W_enc[l]^T); A fused from f32 x ----

__global__ __launch_bounds__(512, 2) void k_encode256(const float* __restrict__ xf,
                                                      const short* __restrict__ webf,
                                                      float* __restrict__ feats_f32,
                                                      short* __restrict__ feats_bf) {
  __shared__ short lds[2][4][8192];
  const int l = blockIdx.z;
  const int row0 = blockIdx.y * 256;
  const int col0 = blockIdx.x * 256;
  const int tid = threadIdx.x;
  const int wave = tid >> 6, lane = tid & 63;
  const int wr = wave >> 2, wc = wave & 3;

  const float* A = xf + (size_t)l * NT * NH + (size_t)row0 * NH;
  const short* B = webf + (size_t)l * NF * NH + (size_t)col0 * NH;

  f32x4 acc[2][2][4][2];
#pragma unroll
  for (int qa = 0; qa < 2; ++qa)
#pragma unroll
    for (int qb = 0; qb < 2; ++qb)
#pragma unroll
      for (int m = 0; m < 4; ++m)
#pragma unroll
        for (int n = 0; n < 2; ++n) {
          f32x4 z = {0.f, 0.f, 0.f, 0.f};
          acc[qa][qb][m][n] = z;
        }

  const int KT = NH / 64;
  F32Half stA0, stA1;
  issue_f32half(stA0, A, NH, 1, 0, tid);
  issue_f32half(stA1, A, NH, 1, 1, tid);
  stage_half(lds[0][2], B, NH, 0, 0, tid, wave);
  stage_half(lds[0][3], B, NH, 0, 1, tid, wave);
  commit_f32half(stA0, lds[0][0], tid);
  commit_f32half(stA1, lds[0][1], tid);
  asm volatile("s_waitcnt vmcnt(0) lgkmcnt(0)" ::: "memory");
  __builtin_amdgcn_s_barrier();

  for (int u = 0; u < KT; ++u) {
    short(*bufc)[8192] = lds[u & 1];
    short(*bufn)[8192] = lds[(u + 1) & 1];
    ktile_flat(bufc, acc, wr, wc, lane,
        [&] {
          if (u + 1 < KT) {
            issue_f32half(stA0, A + (u + 1) * 64, NH, 1, 0, tid);
            issue_f32half(stA1, A + (u + 1) * 64, NH, 1, 1, tid);
            stage_half(bufn[2], B + (u + 1) * 64, NH, 0, 0, tid, wave);
            stage_half(bufn[3], B + (u + 1) * 64, NH, 0, 1, tid, wave);
          }
        },
        [&] {
          if (u + 1 < KT) {
            commit_f32half(stA0, bufn[0], tid);
            commit_f32half(stA1, bufn[1], tid);
          }
        });
  }

  const int lr4 = (lane >> 4) * 4, lc = lane & 15;
  float* outF = feats_f32 + (size_t)l * NT * NF;
  short* outB = feats_bf + (size_t)l * NT * NF;
#pragma unroll
  for (int qa = 0; qa < 2; ++qa)
#pragma unroll
    for (int qb = 0; qb < 2; ++qb)
#pragma unroll
      for (int m = 0; m < 4; ++m)
#pragma unroll
        for (int n = 0; n < 2; ++n)
#pragma unroll
          for (int rg = 0; rg < 4; ++rg) {
            const int rr = row0 + wr * 128 + qa * 64 + m * 16 + lr4 + rg;
            const int cc = col0 + wc * 64 + qb * 32 + n * 16 + lc;
            float v = acc[qa][qb][m][n][rg];
            v = v > 0.f ? v : 0.f;
            outF[(size_t)rr * NF + cc] = v;
            outB[(size_t)rr * NF + cc] = f2bf(v);
          }
}

// ---------------- decode: recon[l] = sum_{s<=l} feats[s] @ W_dec[s,l]^T ----------------
// Packed-bf16 + global_load_lds both operands; BK=64; 128KB LDS; flat tiles.
// z-grid: l = 15 - z (heavy-first); panel-sharing blocks sit 8 apart -> same XCD.

__global__ __launch_bounds__(512, 2) void k_decode256(const short* __restrict__ featsbf,
                                                      const short* __restrict__ wdbf,
                                                      float* __restrict__ recon) {
  __shared__ short lds[2][4][8192];
  const int l = (NL - 1) - blockIdx.z;
  const int row0 = blockIdx.y * 256;  // T
  const int col0 = blockIdx.x * 256;  // H
  const int tid = threadIdx.x;
  const int wave = tid >> 6, lane = tid & 63;
  const int wr = wave >> 2, wc = wave & 3;
  const int pbase = l * (l + 1) / 2;

  const short* Af = featsbf + (size_t)row0 * NF;
  const short* Bw = wdbf + (size_t)col0 * NF;

  f32x4 acc[2][2][4][2];
#pragma unroll
  for (int qa = 0; qa < 2; ++qa)
#pragma unroll
    for (int qb = 0; qb < 2; ++qb)
#pragma unroll
      for (int m = 0; m < 4; ++m)
#pragma unroll
        for (int n = 0; n < 2; ++n) {
          f32x4 z = {0.f, 0.f, 0.f, 0.f};
          acc[qa][qb][m][n] = z;
        }

  const int KT = 8 * (l + 1);
#define ABASE(kt) (Af + (size_t)((kt) >> 3) * (NT * NF) + ((kt)&7) * 64)
#define BBASE(kt) (Bw + (size_t)(pbase + ((kt) >> 3)) * (NH * NF) + ((kt)&7) * 64)

  stage_half(lds[0][0], ABASE(0), NF, 1, 0, tid, wave);
  stage_half(lds[0][1], ABASE(0), NF, 1, 1, tid, wave);
  stage_half(lds[0][2], BBASE(0), NF, 0, 0, tid, wave);
  stage_half(lds[0][3], BBASE(0), NF, 0, 1, tid, wave);
  asm volatile("s_waitcnt vmcnt(0)" ::: "memory");
  __builtin_amdgcn_s_barrier();

  for (int u = 0; u < KT; ++u) {
    short(*bufc)[8192] = lds[u & 1];
    short(*bufn)[8192] = lds[(u + 1) & 1];
    ktile_flat(bufc, acc, wr, wc, lane,
        [&] {
          if (u + 1 < KT) {
            stage_half(bufn[0], ABASE(u + 1), NF, 1, 0, tid, wave);
            stage_half(bufn[1], ABASE(u + 1), NF, 1, 1, tid, wave);
            stage_half(bufn[2], BBASE(u + 1), NF, 0, 0, tid, wave);
            stage_half(bufn[3], BBASE(u + 1), NF, 0, 1, tid, wave);
          }
        },
        [&] {});
  }
#undef ABASE
#undef BBASE

  const int lr4 = (lane >> 4) * 4, lc = lane & 15;
  float* out = recon + (size_t)l * NT * NH;
#pragma unroll
  for (int qa = 0; qa < 2; ++qa)
#pragma unroll
    for (int qb = 0; qb < 2; ++qb)
#pragma unroll
      for (int m = 0; m < 4; ++m)
#pragma unroll
        for (int n = 0; n < 2; ++n)
#pragma unroll
          for (int rg = 0; rg < 4; ++rg) {
            const int rr = row0 + wr * 128 + qa * 64 + m * 16 + lr4 + rg;
            const int cc = col0 + wc * 64 + qb * 32 + n * 16 + lc;
            out[(size_t)rr * NH + cc] = acc[qa][qb][m][n][rg];
          }
}

// ---------------- launch ----------------

extern "C" void kernel_launch(void* const* d_in, const int* in_sizes, int n_in,
                              void* d_out, int out_size, void* d_ws, size_t ws_size,
                              hipStream_t stream) {
  const float* x = (const float*)d_in[0];
  const float* wenc = (const float*)d_in[1];
  const float* wdec = (const float*)d_in[2];

  float* feats_f32 = (float*)d_out;
  float* recon = feats_f32 + (size_t)NL * NT * NF;

  short* we_bf = (short*)d_ws;                           // 32 MiB
  short* wd_bf = we_bf + (size_t)NL * NF * NH;           // 272 MiB
  short* ft_bf = wd_bf + (size_t)NPAIR * NH * NF;        // 32 MiB

  k_cvt_f32_bf16<<<1024, 256, 0, stream>>>(wenc, we_bf, NL * NF * NH / 4);
  k_cvt_wdec<<<dim3(512, NPAIR), 256, 0, stream>>>(wdec, wd_bf);

  k_encode256<<<dim3(2, 8, 16), 512, 0, stream>>>(x, we_bf, feats_f32, ft_bf);
  k_decode256<<<dim3(8, 8, 16), 512, 0, stream>>>(ft_bf, wd_bf, recon);
}